// Round 1
// baseline (318.340 us; speedup 1.0000x reference)
//
#include <hip/hip_runtime.h>

// Adder v2: float4-vectorized base-10 addition with two-level carry-lookahead.
//
// Layout: row = 64 digits (index 0 = most-significant). 16 lanes per row,
// 4 digits (one float4) per lane, 4 rows per wave -> lane l of a wave reads
// float4 index (wave_row_base*16 + l): fully contiguous 1 KiB per wave
// instruction (coalescing sweet spot, 16 B/lane).
//
// Carry chain:
//   level 0 (in-lane): block generate Gb = carry-out of the lane's 4 digits
//     with carry-in 0; block propagate Pb = all four digit sums == 9.
//     (Mutually exclusive: all-9s generates nothing with cin=0.)
//   level 1 (cross-lane): __ballot packs 4 rows x 16 blocks. Each 16-lane
//     group extracts its row's 16-bit field, reverses to LSB-first order,
//     and uses the adder identity: carries of (X + G) where X = P|G obey
//     c_{i+1} = G_i | (P_i & c_i), so C = ((P|G)+G) ^ (P|G) ^ G gives the
//     per-block carry-in bits. Digits are exact small ints in fp32.

__global__ __launch_bounds__(256) void adder_kernel(
    const float4* __restrict__ a,
    const float4* __restrict__ b,
    float4* __restrict__ out,
    long long n_rows)
{
    const int lane = (int)(threadIdx.x & 63);
    const int k    = lane >> 4;        // which of this wave's 4 rows
    const int blk  = lane & 15;        // block within row; 0 = most-significant
    const int pos  = 15 - blk;         // LSB-first position of this block

    const long long wave_id     = (long long)blockIdx.x * 4 + (threadIdx.x >> 6);
    const long long wave_stride = (long long)gridDim.x * 4;
    const long long n_wave_work = (n_rows + 3) >> 2;   // 4 rows per wave

    for (long long w = wave_id; w < n_wave_work; w += wave_stride) {
        const long long row = w * 4 + k;
        const bool ok = row < n_rows;                  // always true here (n_rows % 4 == 0)
        const long long v4 = (ok ? row : 0) * 16 + blk; // == w*64 + lane when in range

        const float4 av = a[v4];
        const float4 bv = b[v4];
        const float s0 = av.x + bv.x;   // more significant
        const float s1 = av.y + bv.y;
        const float s2 = av.z + bv.z;
        const float s3 = av.w + bv.w;   // less significant

        // level 0: block generate (ripple with carry-in 0) and propagate
        float gc = (s3 >= 10.0f) ? 1.0f : 0.0f;
        gc = (s2 + gc >= 10.0f) ? 1.0f : 0.0f;
        gc = (s1 + gc >= 10.0f) ? 1.0f : 0.0f;
        gc = (s0 + gc >= 10.0f) ? 1.0f : 0.0f;
        const bool Gb = (gc != 0.0f);
        const bool Pb = (s0 == 9.0f) && (s1 == 9.0f) &&
                        (s2 == 9.0f) && (s3 == 9.0f);

        // level 1: 16-block carry-lookahead per row (all lanes of the row
        // redundantly compute the same thing -- cheap VALU)
        const unsigned long long g_mask = __ballot(Gb);
        const unsigned long long p_mask = __ballot(Pb);
        unsigned int g16 = (unsigned int)(g_mask >> (k * 16)) & 0xFFFFu;
        unsigned int p16 = (unsigned int)(p_mask >> (k * 16)) & 0xFFFFu;
        g16 = __brev(g16) >> 16;                       // bit blk -> bit (15-blk)
        p16 = __brev(p16) >> 16;
        const unsigned int pg  = p16 | g16;
        const unsigned int c16 = (pg + g16) ^ pg ^ g16; // carry-in per position
        const float cin = (float)((c16 >> pos) & 1u);

        // in-lane ripple with the recovered block carry-in
        const float u3 = s3 + cin; const float c3 = (u3 >= 10.0f) ? 1.0f : 0.0f;
        const float u2 = s2 + c3;  const float c2 = (u2 >= 10.0f) ? 1.0f : 0.0f;
        const float u1 = s1 + c2;  const float c1 = (u1 >= 10.0f) ? 1.0f : 0.0f;
        const float u0 = s0 + c1;  const float c0 = (u0 >= 10.0f) ? 1.0f : 0.0f;

        float4 dv;
        dv.x = u0 - 10.0f * c0;
        dv.y = u1 - 10.0f * c1;
        dv.z = u2 - 10.0f * c2;
        dv.w = u3 - 10.0f * c3;
        if (ok) out[v4] = dv;
    }
}

extern "C" void kernel_launch(void* const* d_in, const int* in_sizes, int n_in,
                              void* d_out, int out_size, void* d_ws, size_t ws_size,
                              hipStream_t stream) {
    const float4* a = (const float4*)d_in[0];
    const float4* b = (const float4*)d_in[1];
    float4* out = (float4*)d_out;

    const long long n_rows  = (long long)in_sizes[0] / 64;   // 524288
    const long long n_waves = (n_rows + 3) / 4;              // 131072 waves of work
    long long blocks = (n_waves + 3) / 4;                    // 4 waves per block
    if (blocks > 2048) blocks = 2048;                        // 8 blocks/CU x 256 CU,
                                                             // grid-stride the rest
    adder_kernel<<<(int)blocks, 256, 0, stream>>>(a, b, out, n_rows);
}

// Round 2
// 309.849 us; speedup vs baseline: 1.0274x; 1.0274x over previous
//
#include <hip/hip_runtime.h>

// Adder v3: float4-vectorized base-10 addition, two-level carry-lookahead,
// one-shot waves with x4 tile unroll for memory-level parallelism.
//
// Layout: row = 64 digits (index 0 = most-significant). A "tile" = 4 rows =
// 64 float4s; 16 lanes per row, 4 digits (one float4) per lane. Each wave
// handles 4 consecutive tiles straight-line: all 8 loads issued up front
// (128 B/lane in flight), then 4 independent carry solves, then 4 stores.
// No grid-stride loop: waves retire fast and the wave launcher pipelines.
//
// Carry math (per tile): in-lane ripple gives block generate Gb; block
// propagate Pb = all four sums == 9 (mutually exclusive with Gb).
// __ballot packs 4 rows x 16 blocks; each 16-lane group extracts its row's
// 16 bits, reverses to LSB-first, and applies the adder identity
// C = ((P|G)+G) ^ (P|G) ^ G  (carries of X+G with X=P|G obey
// c_{i+1} = G_i | (P_i & c_i)). Digits are exact small ints in fp32.

__device__ __forceinline__ float4 add_tile(const float4 av, const float4 bv,
                                           const int k, const int pos) {
    const float s0 = av.x + bv.x;   // most significant of the lane's 4
    const float s1 = av.y + bv.y;
    const float s2 = av.z + bv.z;
    const float s3 = av.w + bv.w;   // least significant

    // block generate (ripple, cin=0) and propagate
    float gc = (s3 >= 10.0f) ? 1.0f : 0.0f;
    gc = (s2 + gc >= 10.0f) ? 1.0f : 0.0f;
    gc = (s1 + gc >= 10.0f) ? 1.0f : 0.0f;
    gc = (s0 + gc >= 10.0f) ? 1.0f : 0.0f;
    const bool Gb = (gc != 0.0f);
    const bool Pb = (s0 == 9.0f) & (s1 == 9.0f) & (s2 == 9.0f) & (s3 == 9.0f);

    // cross-lane 16-block lookahead per row
    const unsigned long long g_mask = __ballot(Gb);
    const unsigned long long p_mask = __ballot(Pb);
    unsigned int g16 = (unsigned int)(g_mask >> (k * 16)) & 0xFFFFu;
    unsigned int p16 = (unsigned int)(p_mask >> (k * 16)) & 0xFFFFu;
    g16 = __brev(g16) >> 16;                 // bit blk -> bit (15-blk), LSB-first
    p16 = __brev(p16) >> 16;
    const unsigned int pg  = p16 | g16;
    const unsigned int c16 = (pg + g16) ^ pg ^ g16;   // carry-in per position
    const float cin = (float)((c16 >> pos) & 1u);

    // in-lane ripple with recovered block carry-in
    const float u3 = s3 + cin; const float c3 = (u3 >= 10.0f) ? 1.0f : 0.0f;
    const float u2 = s2 + c3;  const float c2 = (u2 >= 10.0f) ? 1.0f : 0.0f;
    const float u1 = s1 + c2;  const float c1 = (u1 >= 10.0f) ? 1.0f : 0.0f;
    const float u0 = s0 + c1;  const float c0 = (u0 >= 10.0f) ? 1.0f : 0.0f;

    float4 dv;
    dv.x = u0 - 10.0f * c0;
    dv.y = u1 - 10.0f * c1;
    dv.z = u2 - 10.0f * c2;
    dv.w = u3 - 10.0f * c3;
    return dv;
}

__global__ __launch_bounds__(256) void adder_kernel(
    const float4* __restrict__ a,
    const float4* __restrict__ b,
    float4* __restrict__ out,
    long long n_tiles)   // tiles of 4 rows (64 float4s each)
{
    const int lane = (int)(threadIdx.x & 63);
    const int k    = lane >> 4;          // row within tile
    const int pos  = 15 - (lane & 15);   // LSB-first block position

    const long long wave_id = (long long)blockIdx.x * 4 + (threadIdx.x >> 6);
    const long long t0 = wave_id * 4;    // 4 tiles per wave
    if (t0 >= n_tiles) return;

    if (t0 + 4 <= n_tiles) {
        const long long i0 = t0 * 64 + lane;
        // issue all 8 loads up front: 128 B/lane (8 KiB/wave) in flight
        const float4 a0 = a[i0];
        const float4 b0 = b[i0];
        const float4 a1 = a[i0 + 64];
        const float4 b1 = b[i0 + 64];
        const float4 a2 = a[i0 + 128];
        const float4 b2 = b[i0 + 128];
        const float4 a3 = a[i0 + 192];
        const float4 b3 = b[i0 + 192];

        out[i0]       = add_tile(a0, b0, k, pos);
        out[i0 + 64]  = add_tile(a1, b1, k, pos);
        out[i0 + 128] = add_tile(a2, b2, k, pos);
        out[i0 + 192] = add_tile(a3, b3, k, pos);
    } else {
        // tail (wave-uniform branch; all 64 lanes participate in ballots)
        for (long long t = t0; t < n_tiles; ++t) {
            const long long i = t * 64 + lane;
            out[i] = add_tile(a[i], b[i], k, pos);
        }
    }
}

extern "C" void kernel_launch(void* const* d_in, const int* in_sizes, int n_in,
                              void* d_out, int out_size, void* d_ws, size_t ws_size,
                              hipStream_t stream) {
    const float4* a = (const float4*)d_in[0];
    const float4* b = (const float4*)d_in[1];
    float4* out = (float4*)d_out;

    const long long n_rows  = (long long)in_sizes[0] / 64;   // 524288
    const long long n_tiles = (n_rows + 3) / 4;              // 131072
    const long long n_waves = (n_tiles + 3) / 4;             // 32768 (4 tiles/wave)
    const long long blocks  = (n_waves + 3) / 4;             // 8192 (4 waves/block)
    adder_kernel<<<(int)blocks, 256, 0, stream>>>(a, b, out, n_tiles);
}